// Round 1
// baseline (1382.174 us; speedup 1.0000x reference)
//
#include <hip/hip_runtime.h>
#include <math.h>

#define NBLK 16
#define KD 32
#define NDIM 512        // NBLK*KD
#define INDIM 64
#define DT_C 0.05f
#define TAU_EPS_C 1e-6f
#define ROWS_PER_WG 64

// tanh via hardware exp; saturates correctly for |x| large.
__device__ __forceinline__ float fast_tanh(float x){
    float e = __expf(2.0f * x);
    return 1.0f - 2.0f / (e + 1.0f);
}

// 32-length dot: LDS (float4 reads, broadcast across the 32-lane group) x register weights
__device__ __forceinline__ float dot32_lds(const float* __restrict__ lds, const float* w){
    const float4* v = reinterpret_cast<const float4*>(lds);
    float a0 = 0.f, a1 = 0.f, a2 = 0.f, a3 = 0.f;
    #pragma unroll
    for (int k = 0; k < 8; ++k){
        float4 t = v[k];
        a0 = fmaf(t.x, w[4*k+0], a0);
        a1 = fmaf(t.y, w[4*k+1], a1);
        a2 = fmaf(t.z, w[4*k+2], a2);
        a3 = fmaf(t.w, w[4*k+3], a3);
    }
    return (a0 + a1) + (a2 + a3);
}

__global__ __launch_bounds__(512, 2)
void ltcn_kernel(const float* __restrict__ y_in,
                 const float* __restrict__ u_t,
                 const float* __restrict__ W_in,
                 const float* __restrict__ b_in,
                 const float* __restrict__ W_fwd,
                 const float* __restrict__ b_fwd,
                 const float* __restrict__ W_rec,
                 const float* __restrict__ b_rec,
                 const float* __restrict__ E_l,
                 const float* __restrict__ E_l_r,
                 const float* __restrict__ tau_raw,
                 const int* __restrict__ n_steps_p,
                 float* __restrict__ y_out)
{
    __shared__ float WinT[INDIM * KD];  // W_in transposed: [i][l]
    __shared__ float ybuf[NDIM];
    __shared__ float netoB[NDIM];
    __shared__ float netrB[NDIM];
    __shared__ float net0B[KD];
    __shared__ float ubuf[INDIM];

    const int tid = threadIdx.x;
    const int j = tid >> 5;    // block index 0..15
    const int l = tid & 31;    // within-block element 0..31
    const int ns = n_steps_p[0];

    // ---- per-thread register weights (loaded once per WG) ----
    float Wrec[KD], Wfwd[KD], El[KD], Elr[KD];
    {
        const float* wr = W_rec  + (size_t)(j*KD + l)*KD;
        const float* el = E_l    + (size_t)(j*KD + l)*KD;
        const float* er = E_l_r  + (size_t)(j*KD + l)*KD;
        #pragma unroll
        for (int k = 0; k < KD; ++k){ Wrec[k] = wr[k]; El[k] = el[k]; Elr[k] = er[k]; }
        if (j > 0){
            const float* wf = W_fwd + (size_t)((j-1)*KD + l)*KD;
            #pragma unroll
            for (int k = 0; k < KD; ++k) Wfwd[k] = wf[k];
        } else {
            #pragma unroll
            for (int k = 0; k < KD; ++k) Wfwd[k] = 0.f;
        }
    }
    const float brec = b_rec[j*KD + l];
    const float bfwd = (j > 0) ? b_fwd[(j-1)*KD + l] : 0.f;

    // inv_tau = 1/(softplus(tau)+eps), stable softplus
    float tr = tau_raw[tid];
    float sp = fmaxf(tr, 0.f) + log1pf(__expf(-fabsf(tr)));
    const float inv_tau = 1.0f / (sp + TAU_EPS_C);

    // stage W_in transposed into LDS (once per WG)
    for (int idx = tid; idx < KD * INDIM; idx += 512){
        int ll = idx >> 6;   // 0..31  (row of W_in)
        int ii = idx & 63;   // 0..63  (col of W_in)
        WinT[ii*KD + ll] = W_in[idx];
    }
    __syncthreads();

    const int row0 = blockIdx.x * ROWS_PER_WG;
    for (int r = 0; r < ROWS_PER_WG; ++r){
        const int row = row0 + r;
        float yreg = y_in[(size_t)row * NDIM + tid];
        ybuf[tid] = yreg;
        if (tid < INDIM) ubuf[tid] = u_t[(size_t)row * INDIM + tid];
        __syncthreads();

        // net0 = tanh(u @ W_in^T + b_in): loop-invariant across steps; 32 threads compute it
        if (j == 0){
            float a0 = 0.f, a1 = 0.f;
            #pragma unroll
            for (int i = 0; i < INDIM; i += 2){
                a0 = fmaf(ubuf[i],   WinT[i*KD + l],     a0);
                a1 = fmaf(ubuf[i+1], WinT[(i+1)*KD + l], a1);
            }
            net0B[l] = fast_tanh(a0 + a1 + b_in[l]);
        }
        __syncthreads();
        const float my_net0 = (j == 0) ? net0B[l] : 0.f;

        for (int s = 0; s < ns; ++s){
            // phase 1: read old y (LDS), compute nets
            float netr = fast_tanh(dot32_lds(ybuf + j*KD, Wrec) + brec);
            float neto;
            if (j == 0){
                neto = my_net0;
            } else {
                neto = fast_tanh(dot32_lds(ybuf + (j-1)*KD, Wfwd) + bfwd);
            }
            netoB[tid] = neto;
            netrB[tid] = netr;
            __syncthreads();   // B1: nets visible; all y reads complete

            // phase 2: projection dots + state update
            float outv = dot32_lds(netoB + j*KD, El);
            float recv = dot32_lds(netrB + j*KD, Elr);
            float decay = inv_tau + fabsf(neto) + fabsf(netr);
            yreg = fmaf(DT_C, fmaf(-yreg, decay, outv + recv), yreg);
            ybuf[tid] = yreg;  // safe: all phase-1 y reads finished at B1
            __syncthreads();   // B2: new y visible; net reads complete
        }

        y_out[(size_t)row * NDIM + tid] = yreg;
        // no extra barrier needed: next row writes only thread-own slots first
    }
}

extern "C" void kernel_launch(void* const* d_in, const int* in_sizes, int n_in,
                              void* d_out, int out_size, void* d_ws, size_t ws_size,
                              hipStream_t stream) {
    const float* y       = (const float*)d_in[0];
    const float* u_t     = (const float*)d_in[1];
    const float* W_in    = (const float*)d_in[2];
    const float* b_in    = (const float*)d_in[3];
    const float* W_fwd   = (const float*)d_in[4];
    const float* b_fwd   = (const float*)d_in[5];
    const float* W_rec   = (const float*)d_in[6];
    const float* b_rec   = (const float*)d_in[7];
    const float* E_l     = (const float*)d_in[8];
    const float* E_l_r   = (const float*)d_in[9];
    const float* tau_raw = (const float*)d_in[10];
    const int*   n_steps = (const int*)d_in[11];
    float* out = (float*)d_out;

    const int batch = in_sizes[0] / NDIM;
    const int grid  = batch / ROWS_PER_WG;

    hipLaunchKernelGGL(ltcn_kernel, dim3(grid), dim3(512), 0, stream,
                       y, u_t, W_in, b_in, W_fwd, b_fwd, W_rec, b_rec,
                       E_l, E_l_r, tau_raw, n_steps, out);
}

// Round 2
// 332.057 us; speedup vs baseline: 4.1625x; 4.1625x over previous
//
#include <hip/hip_runtime.h>
#include <hip/hip_bf16.h>
#include <math.h>

#define NBLK 16
#define KD 32
#define NDIM 512        // NBLK*KD
#define INDIM 64
#define DT_C 0.05f
#define TAU_EPS_C 1e-6f
#define MROWS 16        // batch rows per tile (one MFMA M-tile)
#define WGSIZE 1024     // 16 waves; wave j handles block j
#define LSTRIDE (NDIM + 8)   // bf16 elements; +16B pad breaks power-of-2 strides

typedef __attribute__((ext_vector_type(8))) short bf16x8;   // 8 bf16 = 4 VGPRs (MFMA A/B frag)
typedef __attribute__((ext_vector_type(4))) float f32x4;    // MFMA C/D frag

#define MFMA16(a, b, c) __builtin_amdgcn_mfma_f32_16x16x32_bf16((a), (b), (c), 0, 0, 0)

__device__ __forceinline__ float fast_tanh(float x){
    float e = __expf(2.0f * x);
    return 1.0f - 2.0f / (e + 1.0f);
}
__device__ __forceinline__ short f2bf(float f){
    __hip_bfloat16 h = __float2bfloat16(f);   // RNE
    return *reinterpret_cast<short*>(&h);
}
__device__ __forceinline__ float bf2f(unsigned short u){
    unsigned int x = ((unsigned int)u) << 16;
    return *reinterpret_cast<float*>(&x);
}

// B-frag for D = A*B: lane holds B[k=quad*8+jj][n=lane&15].
// For net = y @ W^T we need B[k][n] = W[n][k]: 8 consecutive floats of row n.
__device__ __forceinline__ bf16x8 load_bfrag(const float* __restrict__ W, int l15, int quad, int nt){
    const float* p = W + (size_t)(nt*16 + l15)*KD + quad*8;
    bf16x8 r;
    #pragma unroll
    for (int i = 0; i < 8; ++i) r[i] = f2bf(p[i]);
    return r;
}

__global__ __launch_bounds__(WGSIZE, 4)
void ltcn_mfma_kernel(const float* __restrict__ y_in,
                      const float* __restrict__ u_t,
                      const float* __restrict__ W_in,
                      const float* __restrict__ b_in,
                      const float* __restrict__ W_fwd,
                      const float* __restrict__ b_fwd,
                      const float* __restrict__ W_rec,
                      const float* __restrict__ b_rec,
                      const float* __restrict__ E_l,
                      const float* __restrict__ E_l_r,
                      const float* __restrict__ tau_raw,
                      const int* __restrict__ n_steps_p,
                      float* __restrict__ y_out,
                      int batch)
{
    // A-layout bf16 buffers: [row][col] with padded stride (16B-aligned rows)
    __shared__ __align__(16) unsigned short Ybuf[MROWS * LSTRIDE];
    __shared__ __align__(16) unsigned short NetO[MROWS * LSTRIDE];
    __shared__ __align__(16) unsigned short NetR[MROWS * LSTRIDE];
    __shared__ float WinT[INDIM * KD];      // WinT[i][l] = W_in[l][i]
    __shared__ float Ubuf[MROWS][INDIM];

    const int tid  = threadIdx.x;
    const int j    = tid >> 6;       // wave id = block index 0..15
    const int lane = tid & 63;
    const int quad = lane >> 4;      // 0..3
    const int l15  = lane & 15;
    const int ns   = n_steps_p[0];

    // ---- once per WG: stage WinT, load weight B-frags + per-lane scalars ----
    for (int idx = tid; idx < KD * INDIM; idx += WGSIZE){
        int l = idx >> 6;            // W_in row (0..31)
        int i = idx & 63;            // W_in col (0..63)
        WinT[i*KD + l] = W_in[idx];
    }

    const float* Wr = W_rec  + (size_t)j * KD * KD;
    const float* Wf = W_fwd  + (size_t)((j > 0) ? (j-1) : 0) * KD * KD;
    const float* Ee = E_l    + (size_t)j * KD * KD;
    const float* Er = E_l_r  + (size_t)j * KD * KD;

    bf16x8 Brec[2], Bfwd[2], BEl[2], BElr[2];
    float brec_s[2], bfwd_s[2], invtau_s[2];
    #pragma unroll
    for (int nt = 0; nt < 2; ++nt){
        Brec[nt] = load_bfrag(Wr, l15, quad, nt);
        Bfwd[nt] = load_bfrag(Wf, l15, quad, nt);
        BEl[nt]  = load_bfrag(Ee, l15, quad, nt);
        BElr[nt] = load_bfrag(Er, l15, quad, nt);
        int l = nt*16 + l15;
        brec_s[nt] = b_rec[j*KD + l];
        bfwd_s[nt] = (j > 0) ? b_fwd[(j-1)*KD + l] : 0.f;
        float tr = tau_raw[j*KD + l];
        float sp = fmaxf(tr, 0.f) + log1pf(__expf(-fabsf(tr)));
        invtau_s[nt] = 1.0f / (sp + TAU_EPS_C);
    }
    const float bin_s = b_in[tid & (KD-1)];   // for net0 (only tid<512 uses it)

    const int tiles = batch / MROWS;
    const f32x4 zero = {0.f, 0.f, 0.f, 0.f};

    for (int t = blockIdx.x; t < tiles; t += gridDim.x){
        const int row0 = t * MROWS;

        // ---- load y (fp32 regs at D positions) + bf16 copy into Ybuf ----
        float yv[2][4];
        #pragma unroll
        for (int nt = 0; nt < 2; ++nt)
        #pragma unroll
        for (int r = 0; r < 4; ++r){
            int rr  = quad*4 + r;
            int col = j*KD + nt*16 + l15;
            float v = y_in[(size_t)(row0 + rr)*NDIM + col];
            yv[nt][r] = v;
            Ybuf[rr*LSTRIDE + col] = (unsigned short)f2bf(v);
        }
        // stage u tile
        for (int idx = tid; idx < MROWS*INDIM; idx += WGSIZE)
            (&Ubuf[0][0])[idx] = u_t[(size_t)row0*INDIM + idx];
        __syncthreads();

        // ---- net0 (step-invariant): 512 threads, one 64-dot each ----
        if (tid < MROWS * KD){
            int b = tid >> 5;
            int l = tid & (KD-1);
            const float* ur = &Ubuf[b][0];
            float a0 = 0.f, a1 = 0.f;
            #pragma unroll
            for (int i = 0; i < INDIM; i += 2){
                a0 = fmaf(ur[i],   WinT[i*KD + l],     a0);
                a1 = fmaf(ur[i+1], WinT[(i+1)*KD + l], a1);
            }
            float n0 = fast_tanh(a0 + a1 + bin_s);
            NetO[b*LSTRIDE + l] = (unsigned short)f2bf(n0);  // block-0 cols persist all steps
        }
        __syncthreads();

        float decay[2][4];

        for (int s = 0; s < ns; ++s){
            // ================= phase A: nets =================
            if (j == 0){
                // neto = net0 (already in NetO cols 0..31); just |.| at D positions
                #pragma unroll
                for (int nt = 0; nt < 2; ++nt)
                #pragma unroll
                for (int r = 0; r < 4; ++r){
                    unsigned short h = NetO[(quad*4 + r)*LSTRIDE + nt*16 + l15];
                    decay[nt][r] = fabsf(bf2f(h));
                }
            } else {
                const bf16x8 Af = *reinterpret_cast<const bf16x8*>(
                    &Ybuf[l15*LSTRIDE + (j-1)*KD + quad*8]);
                f32x4 aF0 = MFMA16(Af, Bfwd[0], zero);
                f32x4 aF1 = MFMA16(Af, Bfwd[1], zero);
                #pragma unroll
                for (int nt = 0; nt < 2; ++nt){
                    f32x4 a = nt ? aF1 : aF0;
                    #pragma unroll
                    for (int r = 0; r < 4; ++r){
                        float nf = fast_tanh(a[r] + bfwd_s[nt]);
                        decay[nt][r] = fabsf(nf);
                        NetO[(quad*4 + r)*LSTRIDE + j*KD + nt*16 + l15] =
                            (unsigned short)f2bf(nf);
                    }
                }
            }
            {
                const bf16x8 Ar = *reinterpret_cast<const bf16x8*>(
                    &Ybuf[l15*LSTRIDE + j*KD + quad*8]);
                f32x4 aR0 = MFMA16(Ar, Brec[0], zero);
                f32x4 aR1 = MFMA16(Ar, Brec[1], zero);
                #pragma unroll
                for (int nt = 0; nt < 2; ++nt){
                    f32x4 a = nt ? aR1 : aR0;
                    #pragma unroll
                    for (int r = 0; r < 4; ++r){
                        float nr = fast_tanh(a[r] + brec_s[nt]);
                        decay[nt][r] += fabsf(nr);
                        NetR[(quad*4 + r)*LSTRIDE + j*KD + nt*16 + l15] =
                            (unsigned short)f2bf(nr);
                    }
                }
            }
            __syncthreads();   // B1: nets visible, all Ybuf reads done

            // ================= phase B: projections + update =================
            {
                const bf16x8 AO = *reinterpret_cast<const bf16x8*>(
                    &NetO[l15*LSTRIDE + j*KD + quad*8]);
                const bf16x8 AR = *reinterpret_cast<const bf16x8*>(
                    &NetR[l15*LSTRIDE + j*KD + quad*8]);
                #pragma unroll
                for (int nt = 0; nt < 2; ++nt){
                    f32x4 acc = MFMA16(AR, BElr[nt], zero);
                    acc = MFMA16(AO, BEl[nt], acc);
                    #pragma unroll
                    for (int r = 0; r < 4; ++r){
                        float yo = yv[nt][r];
                        float d  = invtau_s[nt] + decay[nt][r];
                        float yn = fmaf(DT_C, fmaf(-yo, d, acc[r]), yo);
                        yv[nt][r] = yn;
                        Ybuf[(quad*4 + r)*LSTRIDE + j*KD + nt*16 + l15] =
                            (unsigned short)f2bf(yn);
                    }
                }
            }
            __syncthreads();   // B2: new y visible, net reads done
        }

        // ---- store y (fp32 from registers) ----
        #pragma unroll
        for (int nt = 0; nt < 2; ++nt)
        #pragma unroll
        for (int r = 0; r < 4; ++r){
            y_out[(size_t)(row0 + quad*4 + r)*NDIM + j*KD + nt*16 + l15] = yv[nt][r];
        }
        // final B2 of the step loop protects LDS reuse on the next tile
    }
}

extern "C" void kernel_launch(void* const* d_in, const int* in_sizes, int n_in,
                              void* d_out, int out_size, void* d_ws, size_t ws_size,
                              hipStream_t stream) {
    const float* y       = (const float*)d_in[0];
    const float* u_t     = (const float*)d_in[1];
    const float* W_in    = (const float*)d_in[2];
    const float* b_in    = (const float*)d_in[3];
    const float* W_fwd   = (const float*)d_in[4];
    const float* b_fwd   = (const float*)d_in[5];
    const float* W_rec   = (const float*)d_in[6];
    const float* b_rec   = (const float*)d_in[7];
    const float* E_l     = (const float*)d_in[8];
    const float* E_l_r   = (const float*)d_in[9];
    const float* tau_raw = (const float*)d_in[10];
    const int*   n_steps = (const int*)d_in[11];
    float* out = (float*)d_out;

    const int batch = in_sizes[0] / NDIM;
    const int grid  = 256;   // 1 WG/CU; each loops over tiles

    hipLaunchKernelGGL(ltcn_mfma_kernel, dim3(grid), dim3(WGSIZE), 0, stream,
                       y, u_t, W_in, b_in, W_fwd, b_fwd, W_rec, b_rec,
                       E_l, E_l_r, tau_raw, n_steps, out, batch);
}